// Round 11
// baseline (259.980 us; speedup 1.0000x reference)
//
#include <hip/hip_runtime.h>
#include <hip/hip_bf16.h>

#define NN 40000
#define NN64 40064          // 626 * 64, padded row count for A tiles
#define EE 640000
#define CAP 64              // bucket capacity (in-deg ~ Poisson(16); P(>64) ~ 1e-22)

typedef __attribute__((ext_vector_type(8))) short short8;
typedef __attribute__((ext_vector_type(4))) float floatx4;

__device__ inline unsigned short f2bf(float f) {
    unsigned u = __float_as_uint(f);
    unsigned r = (u + 0x7FFFu + ((u >> 16) & 1u)) >> 16;
    return (unsigned short)r;
}
__device__ inline float bflo(unsigned u) { return __uint_as_float(u << 16); }
__device__ inline float bfhi(unsigned u) { return __uint_as_float(u & 0xFFFF0000u); }

// ---- init: weight pack + cursor zero (xy prep now inlined in gemm) ---------
__global__ void init_kernel(const float* __restrict__ Wq, const float* __restrict__ Wk,
                            const float* __restrict__ Wv, const float* __restrict__ Ws,
                            unsigned short* __restrict__ Wp, int* __restrict__ cursor) {
    int idx = blockIdx.x * 256 + threadIdx.x;          // 0..65535
    {                                                  // Wp[mode][n][k] = bf16(W[k][n]*s)
        int mode = idx >> 14;
        int r = idx & 16383;
        int n = r >> 7, k = r & 127;
        const float* W = (mode == 0) ? Wq : (mode == 1) ? Wk : (mode == 2) ? Wv : Ws;
        float val = W[k * 128 + n];
        if (mode == 0) val *= 0.17677669529663687f;    // fold 1/sqrt(D) into Wq
        Wp[idx] = f2bf(val);
    }
    if (idx < NN) cursor[idx] = 0;
}

// ------- MFMA projection GEMM (inline x+emb prep) + concurrent CSR fill -----
// grid (626, 3); block 256 = 4 waves. Tile: 64 rows x 128 cols, K=128.
// y=0: bucket-CSR fill over edges (dispatched FIRST -> overlaps GEMM slices)
// y=1: q then ss -> qss dword (bf16(q*s) | bf16(ss)<<16)
// y=2: k then v  -> kv  dword (bf16(k)   | bf16(v)<<16)
__global__ __launch_bounds__(256) void gemm_mfma(
    const float* __restrict__ x, const int* __restrict__ ylab,
    const float* __restrict__ emb, const unsigned short* __restrict__ Wp,
    const float* __restrict__ bq, const float* __restrict__ bk,
    const float* __restrict__ bv, const float* __restrict__ bs,
    unsigned* __restrict__ qss, unsigned* __restrict__ kvd,
    const int* __restrict__ ei, int* __restrict__ cursor,
    unsigned short* __restrict__ csr) {
    int yb = blockIdx.y;
    if (yb == 0) {                                     // CSR fill, grid-stride
        int t = blockIdx.x * 256 + threadIdx.x;        // 626*256 = 160,256 threads
        for (int e = t; e < EE; e += 626 * 256) {
            int d = ei[EE + e];
            int s = ei[e];
            int pos = atomicAdd(&cursor[d], 1);
            if (pos < CAP) csr[(d << 6) + pos] = (unsigned short)s;
        }
        return;
    }
    int kind = yb - 1;

    __shared__ unsigned short As[64 * 136];            // 17,408 B
    long m0 = (long)blockIdx.x * 64;

    // stage A = bf16(x + emb[ylab]): 4 threads per row, 32 floats each
    {
        int t = threadIdx.x;
        int row = t >> 2, qtr = t & 3;
        long gr = m0 + row;
        uint4* dst = (uint4*)&As[row * 136 + qtr * 32];
        if (gr < NN) {
            const float4* xs = (const float4*)(x + gr * 128 + qtr * 32);
            const float4* es = (const float4*)(emb + ylab[gr] * 128 + qtr * 32);
#pragma unroll
            for (int i = 0; i < 4; ++i) {
                float4 a0 = xs[2 * i],     b0 = es[2 * i];
                float4 a1 = xs[2 * i + 1], b1 = es[2 * i + 1];
                uint4 o;
                o.x = (unsigned)f2bf(a0.x + b0.x) | ((unsigned)f2bf(a0.y + b0.y) << 16);
                o.y = (unsigned)f2bf(a0.z + b0.z) | ((unsigned)f2bf(a0.w + b0.w) << 16);
                o.z = (unsigned)f2bf(a1.x + b1.x) | ((unsigned)f2bf(a1.y + b1.y) << 16);
                o.w = (unsigned)f2bf(a1.z + b1.z) | ((unsigned)f2bf(a1.w + b1.w) << 16);
                dst[i] = o;
            }
        } else {
            uint4 z = {0u, 0u, 0u, 0u};
#pragma unroll
            for (int i = 0; i < 4; ++i) dst[i] = z;
        }
    }
    __syncthreads();

    int w  = threadIdx.x >> 6;                         // wave -> rows w*16..w*16+15
    int ln = threadIdx.x & 15;
    int qd = (threadIdx.x & 63) >> 4;

    short8 afr[4];
#pragma unroll
    for (int kc = 0; kc < 4; ++kc)
        afr[kc] = *(const short8*)&As[(w * 16 + ln) * 136 + kc * 32 + qd * 8];

    long rowb = m0 + w * 16 + qd * 4;

    const unsigned short* Wm1 = Wp + (size_t)((kind == 0) ? 0 : 1) * 16384;
    const unsigned short* Wm2 = Wp + (size_t)((kind == 0) ? 3 : 2) * 16384;
    const float* b1 = (kind == 0) ? bq : bk;
    const float* b2 = (kind == 0) ? bs : bv;
    float b1s = (kind == 0) ? 0.17677669529663687f : 1.0f;
    unsigned* dst = (kind == 0) ? qss : kvd;

    floatx4 acc[8];
#pragma unroll
    for (int ni = 0; ni < 8; ++ni) acc[ni] = (floatx4){0.f, 0.f, 0.f, 0.f};
#pragma unroll
    for (int kc = 0; kc < 4; ++kc) {
        short8 bfr[8];
#pragma unroll
        for (int ni = 0; ni < 8; ++ni)
            bfr[ni] = *(const short8*)&Wm1[(ni * 16 + ln) * 128 + kc * 32 + qd * 8];
#pragma unroll
        for (int ni = 0; ni < 8; ++ni)
            acc[ni] = __builtin_amdgcn_mfma_f32_16x16x32_bf16(
                afr[kc], bfr[ni], acc[ni], 0, 0, 0);
    }
    unsigned lo[8][4];                                 // bf16 stash of first GEMM
#pragma unroll
    for (int ni = 0; ni < 8; ++ni) {
        float bvv = b1[ni * 16 + ln] * b1s;
#pragma unroll
        for (int r = 0; r < 4; ++r) lo[ni][r] = f2bf(acc[ni][r] + bvv);
    }
#pragma unroll
    for (int ni = 0; ni < 8; ++ni) acc[ni] = (floatx4){0.f, 0.f, 0.f, 0.f};
#pragma unroll
    for (int kc = 0; kc < 4; ++kc) {
        short8 bfr[8];
#pragma unroll
        for (int ni = 0; ni < 8; ++ni)
            bfr[ni] = *(const short8*)&Wm2[(ni * 16 + ln) * 128 + kc * 32 + qd * 8];
#pragma unroll
        for (int ni = 0; ni < 8; ++ni)
            acc[ni] = __builtin_amdgcn_mfma_f32_16x16x32_bf16(
                afr[kc], bfr[ni], acc[ni], 0, 0, 0);
    }
#pragma unroll
    for (int ni = 0; ni < 8; ++ni) {
        int col = ni * 16 + ln;
        float bvv = b2[col];
#pragma unroll
        for (int r = 0; r < 4; ++r) {
            long row = rowb + r;
            if (row < NN)
                dst[row * 128 + col] = lo[ni][r] | ((unsigned)f2bf(acc[ni][r] + bvv) << 16);
        }
    }
}

// -------- per-dst online-softmax attention + skip + k-split classifier ------
// 2 nodes per 64-lane wave (8 nodes / 256-thread block).
// lane = half(1b: node) | head(2b) | dimquad(3b): 4 dims/lane via uint4 kv.
// qss packed (q bf16 low, ss bf16 high). csr is ushort indices.
__global__ __launch_bounds__(256) void attn_kernel(
    const unsigned* __restrict__ qss, const uint4* __restrict__ kv4,
    const int* __restrict__ cursor, const unsigned short* __restrict__ csr,
    const float* __restrict__ Wl, const float* __restrict__ bl,
    float* __restrict__ out) {
    __shared__ float P[8][128];
    __shared__ float red[4][8][64];                    // [wave][node][col]
    int w = threadIdx.x >> 6;
    int lane = threadIdx.x & 63;
    int half = lane >> 5;
    int node = w * 2 + half;                           // node within block, 0..7
    int i = blockIdx.x * 8 + node;                     // dst node
    int l5 = lane & 31;                                // uint4 slot: dims 4*l5..4*l5+3
    uint4 qu = ((const uint4*)qss)[i * 32 + l5];
    float q0 = bflo(qu.x), q1 = bflo(qu.y), q2 = bflo(qu.z), q3 = bflo(qu.w);
    float s0 = bfhi(qu.x), s1 = bfhi(qu.y), s2 = bfhi(qu.z), s3 = bfhi(qu.w);
    int cnt = cursor[i];
    if (cnt > CAP) cnt = CAP;
    const unsigned short* lst = csr + (i << 6);
    int cntA = __shfl(cnt, 0, 64);
    int cntB = __shfl(cnt, 32, 64);
    int cntmax = (cntA > cntB) ? cntA : cntB;

    float m = -3.0e38f, l = 0.f, a0 = 0.f, a1 = 0.f, a2 = 0.f, a3 = 0.f;
    for (int p = 0; p < cntmax; p += 4) {
        uint2 jr = *(const uint2*)&lst[p];             // 4 ushort indices
        int j0 = min((int)(jr.x & 0xFFFFu), NN - 1);
        int j1 = min((int)(jr.x >> 16),     NN - 1);
        int j2 = min((int)(jr.y & 0xFFFFu), NN - 1);
        int j3 = min((int)(jr.y >> 16),     NN - 1);
        uint4 u0 = kv4[j0 * 32 + l5];
        uint4 u1 = kv4[j1 * 32 + l5];
        uint4 u2 = kv4[j2 * 32 + l5];
        uint4 u3 = kv4[j3 * 32 + l5];
        float pr0 = fmaf(q3, bflo(u0.w), fmaf(q2, bflo(u0.z), fmaf(q1, bflo(u0.y), q0 * bflo(u0.x))));
        float pr1 = fmaf(q3, bflo(u1.w), fmaf(q2, bflo(u1.z), fmaf(q1, bflo(u1.y), q0 * bflo(u1.x))));
        float pr2 = fmaf(q3, bflo(u2.w), fmaf(q2, bflo(u2.z), fmaf(q1, bflo(u2.y), q0 * bflo(u2.x))));
        float pr3 = fmaf(q3, bflo(u3.w), fmaf(q2, bflo(u3.z), fmaf(q1, bflo(u3.y), q0 * bflo(u3.x))));
#pragma unroll
        for (int s = 4; s; s >>= 1) {                  // reduce within 8-lane head group
            pr0 += __shfl_xor(pr0, s, 64);
            pr1 += __shfl_xor(pr1, s, 64);
            pr2 += __shfl_xor(pr2, s, 64);
            pr3 += __shfl_xor(pr3, s, 64);
        }
        pr0 = (p + 0 < cnt) ? pr0 : -3.0e38f;          // mask half's tail
        pr1 = (p + 1 < cnt) ? pr1 : -3.0e38f;
        pr2 = (p + 2 < cnt) ? pr2 : -3.0e38f;
        pr3 = (p + 3 < cnt) ? pr3 : -3.0e38f;
        float mnew = fmaxf(fmaxf(m, fmaxf(pr0, pr1)), fmaxf(pr2, pr3));
        float sc = __expf(m - mnew);
        float e0 = __expf(pr0 - mnew), e1 = __expf(pr1 - mnew);
        float e2 = __expf(pr2 - mnew), e3 = __expf(pr3 - mnew);
        l  = l * sc + (e0 + e1) + (e2 + e3);
        a0 = fmaf(e3, bfhi(u3.x), fmaf(e2, bfhi(u2.x), fmaf(e1, bfhi(u1.x), fmaf(e0, bfhi(u0.x), a0 * sc))));
        a1 = fmaf(e3, bfhi(u3.y), fmaf(e2, bfhi(u2.y), fmaf(e1, bfhi(u1.y), fmaf(e0, bfhi(u0.y), a1 * sc))));
        a2 = fmaf(e3, bfhi(u3.z), fmaf(e2, bfhi(u2.z), fmaf(e1, bfhi(u1.z), fmaf(e0, bfhi(u0.z), a2 * sc))));
        a3 = fmaf(e3, bfhi(u3.w), fmaf(e2, bfhi(u2.w), fmaf(e1, bfhi(u1.w), fmaf(e0, bfhi(u0.w), a3 * sc))));
        m = mnew;
    }
    float inv = (cnt > 0 && l > 0.f) ? (1.0f / l) : 0.f;
    float4 po;
    po.x = a0 * inv + s0;
    po.y = a1 * inv + s1;
    po.z = a2 * inv + s2;
    po.w = a3 * inv + s3;
    *(float4*)&P[node][l5 * 4] = po;
    __syncthreads();

    // k-split classifier: wave w, lane = col; k-slice [w*32, w*32+32), 8 nodes
    {
        int col = lane;
        const float* WlW = Wl + (size_t)(w * 32) * 64 + col;
        float c[8];
#pragma unroll
        for (int n = 0; n < 8; ++n) c[n] = 0.f;
#pragma unroll 8
        for (int kk = 0; kk < 32; ++kk) {
            float wl = WlW[kk * 64];
            int k = w * 32 + kk;
#pragma unroll
            for (int n = 0; n < 8; ++n) c[n] = fmaf(P[n][k], wl, c[n]);
        }
#pragma unroll
        for (int n = 0; n < 8; ++n) red[w][n][col] = c[n];
    }
    __syncthreads();

#pragma unroll
    for (int t = threadIdx.x; t < 512; t += 256) {
        int n = t >> 6, col = t & 63;
        float s = red[0][n][col] + red[1][n][col] + red[2][n][col] + red[3][n][col];
        out[(long)(blockIdx.x * 8 + n) * 64 + col] = s + bl[col];
    }
}

extern "C" void kernel_launch(void* const* d_in, const int* in_sizes, int n_in,
                              void* d_out, int out_size, void* d_ws, size_t ws_size,
                              hipStream_t stream) {
    const float* x   = (const float*)d_in[0];
    const int*   y   = (const int*)d_in[1];
    const int*   ei  = (const int*)d_in[2];
    const float* emb = (const float*)d_in[3];
    const float* Wq  = (const float*)d_in[4];  const float* bq = (const float*)d_in[5];
    const float* Wk  = (const float*)d_in[6];  const float* bk = (const float*)d_in[7];
    const float* Wv  = (const float*)d_in[8];  const float* bv = (const float*)d_in[9];
    const float* Wsk = (const float*)d_in[10]; const float* bs = (const float*)d_in[11];
    const float* Wl  = (const float*)d_in[12]; const float* bl = (const float*)d_in[13];
    float* out = (float*)d_out;

    char* w = (char*)d_ws;
    unsigned*       qss  = (unsigned*)(w);                       // 20,480,000
    unsigned*       kv   = (unsigned*)(w + 20480000);            // 20,480,000
    unsigned short* csr  = (unsigned short*)(w + 40960000);      //  5,120,000
    unsigned short* Wp   = (unsigned short*)(w + 46080000);      //    131,072
    int*         cursor  = (int*)(w + 46211072);                 //    160,000

    init_kernel<<<256, 256, 0, stream>>>(Wq, Wk, Wv, Wsk, Wp, cursor);
    dim3 gg(NN64 / 64, 3);
    gemm_mfma<<<gg, 256, 0, stream>>>(x, y, emb, Wp, bq, bk, bv, bs, qss, kv,
                                      ei, cursor, csr);
    attn_kernel<<<NN / 8, 256, 0, stream>>>(qss, (const uint4*)kv, cursor, csr,
                                            Wl, bl, out);
}

// Round 12
// 220.641 us; speedup vs baseline: 1.1783x; 1.1783x over previous
//
#include <hip/hip_runtime.h>
#include <hip/hip_bf16.h>

#define NN 40000
#define NN64 40064          // 626 * 64, padded row count for A tiles
#define EE 640000
#define CAP 64              // bucket capacity (in-deg ~ Poisson(16); P(>64) ~ 1e-22)

typedef __attribute__((ext_vector_type(8))) short short8;
typedef __attribute__((ext_vector_type(4))) float floatx4;

__device__ inline unsigned short f2bf(float f) {
    unsigned u = __float_as_uint(f);
    unsigned r = (u + 0x7FFFu + ((u >> 16) & 1u)) >> 16;
    return (unsigned short)r;
}
__device__ inline float bflo(unsigned u) { return __uint_as_float(u << 16); }
__device__ inline float bfhi(unsigned u) { return __uint_as_float(u & 0xFFFF0000u); }

// ---- fused: xyb = bf16(x+emb[y]) (padded), weight pack, cursor zero --------
__global__ void prep_kernel(const float4* __restrict__ x, const int* __restrict__ y,
                            const float4* __restrict__ emb,
                            const float* __restrict__ Wq, const float* __restrict__ Wk,
                            const float* __restrict__ Wv, const float* __restrict__ Ws,
                            uint2* __restrict__ xyb, unsigned short* __restrict__ Wp,
                            int* __restrict__ cursor) {
    int idx = blockIdx.x * 256 + threadIdx.x;          // over NN64*32 slots
    if (idx < NN64 * 32) {
        int n  = idx >> 5;
        int fo = idx & 31;
        uint2 o;
        if (n < NN) {
            float4 a = x[idx];
            float4 b = emb[y[n] * 32 + fo];
            unsigned t0 = f2bf(a.x + b.x), t1 = f2bf(a.y + b.y);
            unsigned t2 = f2bf(a.z + b.z), t3 = f2bf(a.w + b.w);
            o.x = t0 | (t1 << 16);
            o.y = t2 | (t3 << 16);
        } else {
            o.x = 0; o.y = 0;
        }
        xyb[idx] = o;
    }
    if (idx < 65536) {                                 // Wp[mode][n][k] = bf16(W[k][n]*s)
        int mode = idx >> 14;
        int r = idx & 16383;
        int n = r >> 7, k = r & 127;
        const float* W = (mode == 0) ? Wq : (mode == 1) ? Wk : (mode == 2) ? Wv : Ws;
        float val = W[k * 128 + n];
        if (mode == 0) val *= 0.17677669529663687f;    // fold 1/sqrt(D) into Wq
        Wp[idx] = f2bf(val);
    }
    if (idx < NN) cursor[idx] = 0;
}

// ------------- MFMA projection GEMM + concurrent CSR fill -------------------
// grid (626, 3); block 256 = 4 waves. Tile: 64 rows x 128 cols, K=128.
// y=0: q then ss -> qss dword (bf16(q*s) | bf16(ss)<<16)
// y=1: k then v  -> kv  dword (bf16(k)   | bf16(v)<<16)
// y=2: bucket-CSR fill over edges (int csr: 4-byte stores, R8-measured best).
__global__ __launch_bounds__(256) void gemm_mfma(
    const unsigned short* __restrict__ Axy, const unsigned short* __restrict__ Wp,
    const float* __restrict__ bq, const float* __restrict__ bk,
    const float* __restrict__ bv, const float* __restrict__ bs,
    unsigned* __restrict__ qss, unsigned* __restrict__ kvd,
    const int* __restrict__ ei, int* __restrict__ cursor, int* __restrict__ csr) {
    int kind = blockIdx.y;
    if (kind == 2) {                                   // CSR fill, grid-stride
        int t = blockIdx.x * 256 + threadIdx.x;        // 626*256 = 160,256 threads
        for (int e = t; e < EE; e += 626 * 256) {
            int d = ei[EE + e];
            int s = ei[e];
            int pos = atomicAdd(&cursor[d], 1);
            if (pos < CAP) csr[(d << 6) + pos] = s;
        }
        return;
    }

    __shared__ unsigned short As[64 * 136];            // 17,408 B
    long m0 = (long)blockIdx.x * 64;

    // stage A: 4 threads per row, 32 shorts = 4x uint4 (64 B) each
    {
        int t = threadIdx.x;
        int row = t >> 2, qtr = t & 3;
        const uint4* src = (const uint4*)(Axy + (m0 + row) * 128 + qtr * 32);
        uint4* dst = (uint4*)&As[row * 136 + qtr * 32];
#pragma unroll
        for (int i = 0; i < 4; ++i) dst[i] = src[i];
    }
    __syncthreads();

    int w  = threadIdx.x >> 6;                         // wave -> rows w*16..w*16+15
    int ln = threadIdx.x & 15;
    int qd = (threadIdx.x & 63) >> 4;

    short8 afr[4];
#pragma unroll
    for (int kc = 0; kc < 4; ++kc)
        afr[kc] = *(const short8*)&As[(w * 16 + ln) * 136 + kc * 32 + qd * 8];

    long rowb = m0 + w * 16 + qd * 4;

    const unsigned short* Wm1 = Wp + (size_t)((kind == 0) ? 0 : 1) * 16384;
    const unsigned short* Wm2 = Wp + (size_t)((kind == 0) ? 3 : 2) * 16384;
    const float* b1 = (kind == 0) ? bq : bk;
    const float* b2 = (kind == 0) ? bs : bv;
    float b1s = (kind == 0) ? 0.17677669529663687f : 1.0f;
    unsigned* dst = (kind == 0) ? qss : kvd;

    floatx4 acc[8];
#pragma unroll
    for (int ni = 0; ni < 8; ++ni) acc[ni] = (floatx4){0.f, 0.f, 0.f, 0.f};
#pragma unroll
    for (int kc = 0; kc < 4; ++kc) {
        short8 bfr[8];
#pragma unroll
        for (int ni = 0; ni < 8; ++ni)
            bfr[ni] = *(const short8*)&Wm1[(ni * 16 + ln) * 128 + kc * 32 + qd * 8];
#pragma unroll
        for (int ni = 0; ni < 8; ++ni)
            acc[ni] = __builtin_amdgcn_mfma_f32_16x16x32_bf16(
                afr[kc], bfr[ni], acc[ni], 0, 0, 0);
    }
    unsigned lo[8][4];                                 // bf16 stash of first GEMM
#pragma unroll
    for (int ni = 0; ni < 8; ++ni) {
        float bvv = b1[ni * 16 + ln] * b1s;
#pragma unroll
        for (int r = 0; r < 4; ++r) lo[ni][r] = f2bf(acc[ni][r] + bvv);
    }
#pragma unroll
    for (int ni = 0; ni < 8; ++ni) acc[ni] = (floatx4){0.f, 0.f, 0.f, 0.f};
#pragma unroll
    for (int kc = 0; kc < 4; ++kc) {
        short8 bfr[8];
#pragma unroll
        for (int ni = 0; ni < 8; ++ni)
            bfr[ni] = *(const short8*)&Wm2[(ni * 16 + ln) * 128 + kc * 32 + qd * 8];
#pragma unroll
        for (int ni = 0; ni < 8; ++ni)
            acc[ni] = __builtin_amdgcn_mfma_f32_16x16x32_bf16(
                afr[kc], bfr[ni], acc[ni], 0, 0, 0);
    }
#pragma unroll
    for (int ni = 0; ni < 8; ++ni) {
        int col = ni * 16 + ln;
        float bvv = b2[col];
#pragma unroll
        for (int r = 0; r < 4; ++r) {
            long row = rowb + r;
            if (row < NN)
                dst[row * 128 + col] = lo[ni][r] | ((unsigned)f2bf(acc[ni][r] + bvv) << 16);
        }
    }
}

// -------- per-dst online-softmax attention + skip + k-split classifier ------
// 2 nodes per 64-lane wave (8 nodes / 256-thread block).
// lane = half(1b: node) | head(2b) | dimquad(3b): 4 dims/lane via uint4 kv.
// qss packed (q bf16 low, ss bf16 high). csr is int indices.
__global__ __launch_bounds__(256) void attn_kernel(
    const unsigned* __restrict__ qss, const uint4* __restrict__ kv4,
    const int* __restrict__ cursor, const int* __restrict__ csr,
    const float* __restrict__ Wl, const float* __restrict__ bl,
    float* __restrict__ out) {
    __shared__ float P[8][128];
    __shared__ float red[4][8][64];                    // [wave][node][col]
    int w = threadIdx.x >> 6;
    int lane = threadIdx.x & 63;
    int half = lane >> 5;
    int node = w * 2 + half;                           // node within block, 0..7
    int i = blockIdx.x * 8 + node;                     // dst node
    int l5 = lane & 31;                                // uint4 slot: dims 4*l5..4*l5+3
    uint4 qu = ((const uint4*)qss)[i * 32 + l5];
    float q0 = bflo(qu.x), q1 = bflo(qu.y), q2 = bflo(qu.z), q3 = bflo(qu.w);
    float s0 = bfhi(qu.x), s1 = bfhi(qu.y), s2 = bfhi(qu.z), s3 = bfhi(qu.w);
    int cnt = cursor[i];
    if (cnt > CAP) cnt = CAP;
    const int* lst = csr + (i << 6);
    int cntA = __shfl(cnt, 0, 64);
    int cntB = __shfl(cnt, 32, 64);
    int cntmax = (cntA > cntB) ? cntA : cntB;

    float m = -3.0e38f, l = 0.f, a0 = 0.f, a1 = 0.f, a2 = 0.f, a3 = 0.f;
    for (int p = 0; p < cntmax; p += 4) {
        int4 j4 = *(const int4*)&lst[p];               // 4 int indices
        int j0 = (int)min((unsigned)j4.x, (unsigned)(NN - 1));   // clamp poison slots
        int j1 = (int)min((unsigned)j4.y, (unsigned)(NN - 1));
        int j2 = (int)min((unsigned)j4.z, (unsigned)(NN - 1));
        int j3 = (int)min((unsigned)j4.w, (unsigned)(NN - 1));
        uint4 u0 = kv4[j0 * 32 + l5];
        uint4 u1 = kv4[j1 * 32 + l5];
        uint4 u2 = kv4[j2 * 32 + l5];
        uint4 u3 = kv4[j3 * 32 + l5];
        float pr0 = fmaf(q3, bflo(u0.w), fmaf(q2, bflo(u0.z), fmaf(q1, bflo(u0.y), q0 * bflo(u0.x))));
        float pr1 = fmaf(q3, bflo(u1.w), fmaf(q2, bflo(u1.z), fmaf(q1, bflo(u1.y), q0 * bflo(u1.x))));
        float pr2 = fmaf(q3, bflo(u2.w), fmaf(q2, bflo(u2.z), fmaf(q1, bflo(u2.y), q0 * bflo(u2.x))));
        float pr3 = fmaf(q3, bflo(u3.w), fmaf(q2, bflo(u3.z), fmaf(q1, bflo(u3.y), q0 * bflo(u3.x))));
#pragma unroll
        for (int s = 4; s; s >>= 1) {                  // reduce within 8-lane head group
            pr0 += __shfl_xor(pr0, s, 64);
            pr1 += __shfl_xor(pr1, s, 64);
            pr2 += __shfl_xor(pr2, s, 64);
            pr3 += __shfl_xor(pr3, s, 64);
        }
        pr0 = (p + 0 < cnt) ? pr0 : -3.0e38f;          // mask half's tail
        pr1 = (p + 1 < cnt) ? pr1 : -3.0e38f;
        pr2 = (p + 2 < cnt) ? pr2 : -3.0e38f;
        pr3 = (p + 3 < cnt) ? pr3 : -3.0e38f;
        float mnew = fmaxf(fmaxf(m, fmaxf(pr0, pr1)), fmaxf(pr2, pr3));
        float sc = __expf(m - mnew);
        float e0 = __expf(pr0 - mnew), e1 = __expf(pr1 - mnew);
        float e2 = __expf(pr2 - mnew), e3 = __expf(pr3 - mnew);
        l  = l * sc + (e0 + e1) + (e2 + e3);
        a0 = fmaf(e3, bfhi(u3.x), fmaf(e2, bfhi(u2.x), fmaf(e1, bfhi(u1.x), fmaf(e0, bfhi(u0.x), a0 * sc))));
        a1 = fmaf(e3, bfhi(u3.y), fmaf(e2, bfhi(u2.y), fmaf(e1, bfhi(u1.y), fmaf(e0, bfhi(u0.y), a1 * sc))));
        a2 = fmaf(e3, bfhi(u3.z), fmaf(e2, bfhi(u2.z), fmaf(e1, bfhi(u1.z), fmaf(e0, bfhi(u0.z), a2 * sc))));
        a3 = fmaf(e3, bfhi(u3.w), fmaf(e2, bfhi(u2.w), fmaf(e1, bfhi(u1.w), fmaf(e0, bfhi(u0.w), a3 * sc))));
        m = mnew;
    }
    float inv = (cnt > 0 && l > 0.f) ? (1.0f / l) : 0.f;
    float4 po;
    po.x = a0 * inv + s0;
    po.y = a1 * inv + s1;
    po.z = a2 * inv + s2;
    po.w = a3 * inv + s3;
    *(float4*)&P[node][l5 * 4] = po;
    __syncthreads();

    // k-split classifier: wave w, lane = col; k-slice [w*32, w*32+32), 8 nodes
    {
        int col = lane;
        const float* WlW = Wl + (size_t)(w * 32) * 64 + col;
        float c[8];
#pragma unroll
        for (int n = 0; n < 8; ++n) c[n] = 0.f;
#pragma unroll 8
        for (int kk = 0; kk < 32; ++kk) {
            float wl = WlW[kk * 64];
            int k = w * 32 + kk;
#pragma unroll
            for (int n = 0; n < 8; ++n) c[n] = fmaf(P[n][k], wl, c[n]);
        }
#pragma unroll
        for (int n = 0; n < 8; ++n) red[w][n][col] = c[n];
    }
    __syncthreads();

#pragma unroll
    for (int t = threadIdx.x; t < 512; t += 256) {
        int n = t >> 6, col = t & 63;
        float s = red[0][n][col] + red[1][n][col] + red[2][n][col] + red[3][n][col];
        out[(long)(blockIdx.x * 8 + n) * 64 + col] = s + bl[col];
    }
}

extern "C" void kernel_launch(void* const* d_in, const int* in_sizes, int n_in,
                              void* d_out, int out_size, void* d_ws, size_t ws_size,
                              hipStream_t stream) {
    const float* x   = (const float*)d_in[0];
    const int*   y   = (const int*)d_in[1];
    const int*   ei  = (const int*)d_in[2];
    const float* emb = (const float*)d_in[3];
    const float* Wq  = (const float*)d_in[4];  const float* bq = (const float*)d_in[5];
    const float* Wk  = (const float*)d_in[6];  const float* bk = (const float*)d_in[7];
    const float* Wv  = (const float*)d_in[8];  const float* bv = (const float*)d_in[9];
    const float* Wsk = (const float*)d_in[10]; const float* bs = (const float*)d_in[11];
    const float* Wl  = (const float*)d_in[12]; const float* bl = (const float*)d_in[13];
    float* out = (float*)d_out;

    char* w = (char*)d_ws;
    unsigned*       qss  = (unsigned*)(w);                       // 20,480,000
    unsigned*       kv   = (unsigned*)(w + 20480000);            // 20,480,000
    unsigned short* xyb  = (unsigned short*)(w + 40960000);      // 10,256,384 (NN64 rows)
    int*            csr  = (int*)(w + 51216384);                 // 10,240,000
    unsigned short* Wp   = (unsigned short*)(w + 61456384);      //    131,072
    int*         cursor  = (int*)(w + 61587456);                 //    160,000

    prep_kernel<<<NN64 * 32 / 256, 256, 0, stream>>>(
        (const float4*)x, y, (const float4*)emb, Wq, Wk, Wv, Wsk,
        (uint2*)xyb, Wp, cursor);
    dim3 gg(NN64 / 64, 3);
    gemm_mfma<<<gg, 256, 0, stream>>>(xyb, Wp, bq, bk, bv, bs, qss, kv,
                                      ei, cursor, csr);
    attn_kernel<<<NN / 8, 256, 0, stream>>>(qss, (const uint4*)kv, cursor, csr,
                                            Wl, bl, out);
}